// Round 8
// baseline (127.809 us; speedup 1.0000x reference)
//
#include <hip/hip_runtime.h>

#define ORDER 8
#define FDIM 4096
#define NROWS 8192
#define THREADS 256
#define RPB 2             // rows of x per block (main) — keeps VGPR ~90 (R1 lesson)
#define F4T 4             // fvec4 chunks per thread per row: 4096/4/256
#define F4DIM (FDIM/4)    // 1024 fvec4 per row
#define NPAIR 36          // upper-triangular pairs of 8
#define STHREADS 1024     // setup kernel block size (1 fvec4 column per thread)

typedef float fvec4 __attribute__((ext_vector_type(4)));

// ---------------------------------------------------------------------------
// Setup (ONE block, 1024 threads — one fvec4 column per thread):
//   1. reparam v rows, row norms (16-wave block reduce), vn = v/||v||
//   2. reparam d (kept in reg) and bias (written)
//   3. Gram G[i][j] = vn_i . vn_j  (36 pairs, block reduce)
//   4. thread 0: compact-WY factor T (H0..H7 = I - V^T T V)
//   5. Md[i] = -(sum_{m>=i} T[i][m] vn_m) * d   (rank-8 combine matrix)
// Single kernel: saves a launch + inter-kernel gap vs R6's prep+gramT.
// ---------------------------------------------------------------------------
__global__ __launch_bounds__(STHREADS) void obd_setup(
    const float* __restrict__ v_mean, const float* __restrict__ v_logvar,
    const float* __restrict__ eps_v,
    const float* __restrict__ d_mean, const float* __restrict__ d_logvar,
    const float* __restrict__ eps_d,
    const float* __restrict__ b_mean, const float* __restrict__ b_logvar,
    const float* __restrict__ eps_b,
    float* __restrict__ vn, float* __restrict__ dsc, float* __restrict__ bias,
    float* __restrict__ Md)
{
    const int t = threadIdx.x;          // fvec4 column index, 0..1023
    const int wave = t >> 6, lane = t & 63;
    const int NW = STHREADS / 64;       // 16 waves

    __shared__ float sred[NW][ORDER];
    __shared__ float gred[NW][NPAIR];
    __shared__ float Tsh[ORDER * ORDER];

    const fvec4* vmv = (const fvec4*)v_mean;
    const fvec4* vlv = (const fvec4*)v_logvar;
    const fvec4* evv = (const fvec4*)eps_v;

    // 1. reparam + self-dots
    fvec4 val[ORDER];
    float ss[ORDER];
    #pragma unroll
    for (int i = 0; i < ORDER; ++i) {
        const int idx = i * F4DIM + t;
        fvec4 m = vmv[idx], l = vlv[idx], e = evv[idx];
        fvec4 v;
        #pragma unroll
        for (int c = 0; c < 4; ++c)
            v[c] = fmaf(expf(0.5f * l[c]), e[c], m[c]);
        val[i] = v;
        ss[i] = v[0]*v[0] + v[1]*v[1] + v[2]*v[2] + v[3]*v[3];
    }
    #pragma unroll
    for (int off = 32; off; off >>= 1)
        #pragma unroll
        for (int i = 0; i < ORDER; ++i) ss[i] += __shfl_xor(ss[i], off);
    if (lane == 0)
        #pragma unroll
        for (int i = 0; i < ORDER; ++i) sred[wave][i] = ss[i];
    __syncthreads();
    #pragma unroll
    for (int i = 0; i < ORDER; ++i) {
        float tot = 0.f;
        for (int w = 0; w < NW; ++w) tot += sred[w][i];
        val[i] *= (1.0f / sqrtf(tot));          // val is now vn_i chunk
    }
    // write vn for the main kernel
    fvec4* vnv = (fvec4*)vn;
    #pragma unroll
    for (int i = 0; i < ORDER; ++i) vnv[i * F4DIM + t] = val[i];

    // 2. d and bias reparam (fvec4 column t)
    const fvec4 dm = ((const fvec4*)d_mean)[t];
    const fvec4 dl = ((const fvec4*)d_logvar)[t];
    const fvec4 de = ((const fvec4*)eps_d)[t];
    fvec4 dd;
    #pragma unroll
    for (int c = 0; c < 4; ++c) dd[c] = fmaf(expf(0.5f * dl[c]), de[c], dm[c]);
    ((fvec4*)dsc)[t] = dd;

    const fvec4 bm = ((const fvec4*)b_mean)[t];
    const fvec4 bl = ((const fvec4*)b_logvar)[t];
    const fvec4 be = ((const fvec4*)eps_b)[t];
    fvec4 bb;
    #pragma unroll
    for (int c = 0; c < 4; ++c) bb[c] = fmaf(expf(0.5f * bl[c]), be[c], bm[c]);
    ((fvec4*)bias)[t] = bb;

    // 3. Gram (normalized)
    float g[NPAIR];
    {
        int p = 0;
        #pragma unroll
        for (int i = 0; i < ORDER; ++i)
            #pragma unroll
            for (int j = i; j < ORDER; ++j) {
                g[p] = val[i][0]*val[j][0] + val[i][1]*val[j][1]
                     + val[i][2]*val[j][2] + val[i][3]*val[j][3];
                ++p;
            }
    }
    #pragma unroll
    for (int off = 32; off; off >>= 1)
        #pragma unroll
        for (int p = 0; p < NPAIR; ++p) g[p] += __shfl_xor(g[p], off);
    if (lane == 0)
        #pragma unroll
        for (int p = 0; p < NPAIR; ++p) gred[wave][p] = g[p];
    __syncthreads();

    // 4. T on thread 0
    if (t == 0) {
        float G[ORDER][ORDER];
        int p = 0;
        for (int i = 0; i < ORDER; ++i)
            for (int j = i; j < ORDER; ++j) {
                float s = 0.f;
                for (int w = 0; w < NW; ++w) s += gred[w][p];
                G[i][j] = s;
                ++p;
            }
        float T[ORDER][ORDER];
        for (int i = 0; i < ORDER; ++i)
            for (int j = 0; j < ORDER; ++j) T[i][j] = 0.f;
        T[0][0] = 2.f;
        for (int j = 1; j < ORDER; ++j) {
            for (int i = 0; i < j; ++i) {
                float s = 0.f;
                for (int m = i; m < j; ++m) s += T[i][m] * G[m][j];
                T[i][j] = -2.f * s;
            }
            T[j][j] = 2.f;
        }
        for (int i = 0; i < ORDER; ++i)
            for (int j = 0; j < ORDER; ++j) Tsh[i * ORDER + j] = T[i][j];
    }
    __syncthreads();

    // 5. Md[i] = -(sum_{m>=i} T[i][m] vn_m) * d
    fvec4* Mdv = (fvec4*)Md;
    #pragma unroll
    for (int i = 0; i < ORDER; ++i) {
        fvec4 s = {0.f, 0.f, 0.f, 0.f};
        #pragma unroll
        for (int m = 0; m < ORDER; ++m) {
            if (m >= i) {
                const float tv = Tsh[i * ORDER + m];
                #pragma unroll
                for (int c = 0; c < 4; ++c) s[c] = fmaf(tv, val[m][c], s[c]);
            }
        }
        Mdv[i * F4DIM + t] = -(s * dd);
    }
}

// ---------------------------------------------------------------------------
// Main (monolithic WY, RPB=2): x held in registers across ONE barrier.
//   pass 1: p[rr][i] = row_rr . vn_i   (8 dots per row, one sweep)
//   wave butterfly + one LDS hop (4 waves) -> complete dots everywhere
//   pass 2: out = x*d + sum_i p_i * Md_i + bias   (held x, plain store)
// RPB=2 keeps held-x at 32 VGPR (R3's RPB=4 needed 64 -> 128 total ->
// occupancy 19.5%; R1 @80 VGPR was fastest). Grid 4096 = 16 blocks/CU churn.
// ---------------------------------------------------------------------------
__global__ __launch_bounds__(THREADS, 4) void obd_wy(
    const float* __restrict__ x, const float* __restrict__ vn,
    const float* __restrict__ Md, const float* __restrict__ dsc,
    const float* __restrict__ bias, float* __restrict__ out)
{
    const int t = threadIdx.x;
    const int wave = t >> 6, lane = t & 63;
    const size_t row0 = (size_t)blockIdx.x * RPB;
    const fvec4* xv = (const fvec4*)x;
    const fvec4* Vv = (const fvec4*)vn;
    fvec4* ov = (fvec4*)out;

    __shared__ float red[THREADS / 64][RPB * ORDER];

    // hold x (2 rows x 4 chunks = 32 VGPR)
    fvec4 r[RPB][F4T];
    #pragma unroll
    for (int rr = 0; rr < RPB; ++rr) {
        const size_t base = (row0 + rr) * F4DIM;
        #pragma unroll
        for (int k = 0; k < F4T; ++k)
            r[rr][k] = xv[base + t + k * THREADS];
    }

    // pass 1: dots
    float p[RPB][ORDER];
    #pragma unroll
    for (int rr = 0; rr < RPB; ++rr)
        #pragma unroll
        for (int i = 0; i < ORDER; ++i) p[rr][i] = 0.f;

    #pragma unroll
    for (int k = 0; k < F4T; ++k) {
        const int idx = t + k * THREADS;
        #pragma unroll
        for (int i = 0; i < ORDER; ++i) {
            const fvec4 vc = Vv[i * F4DIM + idx];
            #pragma unroll
            for (int rr = 0; rr < RPB; ++rr)
                #pragma unroll
                for (int c = 0; c < 4; ++c)
                    p[rr][i] = fmaf(r[rr][k][c], vc[c], p[rr][i]);
        }
    }
    #pragma unroll
    for (int off = 32; off; off >>= 1)
        #pragma unroll
        for (int rr = 0; rr < RPB; ++rr)
            #pragma unroll
            for (int i = 0; i < ORDER; ++i)
                p[rr][i] += __shfl_xor(p[rr][i], off);
    if (lane == 0) {
        #pragma unroll
        for (int rr = 0; rr < RPB; ++rr)
            #pragma unroll
            for (int i = 0; i < ORDER; ++i)
                red[wave][rr * ORDER + i] = p[rr][i];
    }
    __syncthreads();
    #pragma unroll
    for (int rr = 0; rr < RPB; ++rr)
        #pragma unroll
        for (int i = 0; i < ORDER; ++i)
            p[rr][i] = red[0][rr * ORDER + i] + red[1][rr * ORDER + i]
                     + red[2][rr * ORDER + i] + red[3][rr * ORDER + i];

    // pass 2: combine on held x + plain store
    const fvec4* Mdv = (const fvec4*)Md;
    const fvec4* dv  = (const fvec4*)dsc;
    const fvec4* bv  = (const fvec4*)bias;
    #pragma unroll
    for (int k = 0; k < F4T; ++k) {
        const int idx = t + k * THREADS;
        const fvec4 dd = dv[idx];
        const fvec4 bb = bv[idx];
        fvec4 acc[RPB];
        #pragma unroll
        for (int rr = 0; rr < RPB; ++rr)
            #pragma unroll
            for (int c = 0; c < 4; ++c)
                acc[rr][c] = fmaf(r[rr][k][c], dd[c], bb[c]);
        #pragma unroll
        for (int i = 0; i < ORDER; ++i) {
            const fvec4 md = Mdv[i * F4DIM + idx];
            #pragma unroll
            for (int rr = 0; rr < RPB; ++rr)
                #pragma unroll
                for (int c = 0; c < 4; ++c)
                    acc[rr][c] = fmaf(p[rr][i], md[c], acc[rr][c]);
        }
        #pragma unroll
        for (int rr = 0; rr < RPB; ++rr)
            ov[(row0 + rr) * F4DIM + idx] = acc[rr];
    }
}

extern "C" void kernel_launch(void* const* d_in, const int* in_sizes, int n_in,
                              void* d_out, int out_size, void* d_ws, size_t ws_size,
                              hipStream_t stream) {
    const float* x        = (const float*)d_in[0];
    const float* v_mean   = (const float*)d_in[1];
    const float* v_logvar = (const float*)d_in[2];
    const float* d_mean   = (const float*)d_in[3];
    const float* d_logvar = (const float*)d_in[4];
    const float* b_mean   = (const float*)d_in[5];
    const float* b_logvar = (const float*)d_in[6];
    const float* eps_v    = (const float*)d_in[7];
    const float* eps_d    = (const float*)d_in[8];
    const float* eps_b    = (const float*)d_in[9];

    float* ws   = (float*)d_ws;
    float* vn   = ws;                        // 8*4096
    float* dsc  = vn + ORDER * FDIM;         // 4096
    float* bias = dsc + FDIM;                // 4096
    float* Md   = bias + FDIM;               // 8*4096

    obd_setup<<<1, STHREADS, 0, stream>>>(
        v_mean, v_logvar, eps_v, d_mean, d_logvar, eps_d,
        b_mean, b_logvar, eps_b, vn, dsc, bias, Md);
    obd_wy<<<NROWS / RPB, THREADS, 0, stream>>>(
        x, vn, Md, dsc, bias, (float*)d_out);
}

// Round 9
// 96.634 us; speedup vs baseline: 1.3226x; 1.3226x over previous
//
#include <hip/hip_runtime.h>

#define ORDER 8
#define FDIM 4096
#define NROWS 8192
#define THREADS 256
#define RPB 2             // rows of x per block: held-x = 32 VGPR
#define F4T 4             // fvec4 chunks per thread per row: 4096/4/256
#define F4DIM (FDIM/4)    // 1024 fvec4 per row
#define NPAIR 36          // upper-triangular pairs of 8
#define STHREADS 1024     // setup kernel block size (1 fvec4 column per thread)

typedef float fvec4 __attribute__((ext_vector_type(4)));

// ---------------------------------------------------------------------------
// Setup (ONE block, 1024 threads — one fvec4 column per thread):
//   1. reparam v rows, row norms (16-wave block reduce), vn = v/||v||
//   2. reparam d (kept in reg) and bias (written)
//   3. Gram G[i][j] = vn_i . vn_j  (36 pairs, block reduce)
//   4. thread 0: compact-WY factor T (H0..H7 = I - V^T T V)
//   5. Md[i] = -(sum_{m>=i} T[i][m] vn_m) * d   (rank-8 combine matrix)
// ---------------------------------------------------------------------------
__global__ __launch_bounds__(STHREADS) void obd_setup(
    const float* __restrict__ v_mean, const float* __restrict__ v_logvar,
    const float* __restrict__ eps_v,
    const float* __restrict__ d_mean, const float* __restrict__ d_logvar,
    const float* __restrict__ eps_d,
    const float* __restrict__ b_mean, const float* __restrict__ b_logvar,
    const float* __restrict__ eps_b,
    float* __restrict__ vn, float* __restrict__ dsc, float* __restrict__ bias,
    float* __restrict__ Md)
{
    const int t = threadIdx.x;          // fvec4 column index, 0..1023
    const int wave = t >> 6, lane = t & 63;
    const int NW = STHREADS / 64;       // 16 waves

    __shared__ float sred[NW][ORDER];
    __shared__ float gred[NW][NPAIR];
    __shared__ float Tsh[ORDER * ORDER];

    const fvec4* vmv = (const fvec4*)v_mean;
    const fvec4* vlv = (const fvec4*)v_logvar;
    const fvec4* evv = (const fvec4*)eps_v;

    // 1. reparam + self-dots
    fvec4 val[ORDER];
    float ss[ORDER];
    #pragma unroll
    for (int i = 0; i < ORDER; ++i) {
        const int idx = i * F4DIM + t;
        fvec4 m = vmv[idx], l = vlv[idx], e = evv[idx];
        fvec4 v;
        #pragma unroll
        for (int c = 0; c < 4; ++c)
            v[c] = fmaf(expf(0.5f * l[c]), e[c], m[c]);
        val[i] = v;
        ss[i] = v[0]*v[0] + v[1]*v[1] + v[2]*v[2] + v[3]*v[3];
    }
    #pragma unroll
    for (int off = 32; off; off >>= 1)
        #pragma unroll
        for (int i = 0; i < ORDER; ++i) ss[i] += __shfl_xor(ss[i], off);
    if (lane == 0)
        #pragma unroll
        for (int i = 0; i < ORDER; ++i) sred[wave][i] = ss[i];
    __syncthreads();
    #pragma unroll
    for (int i = 0; i < ORDER; ++i) {
        float tot = 0.f;
        for (int w = 0; w < NW; ++w) tot += sred[w][i];
        val[i] *= (1.0f / sqrtf(tot));          // val is now vn_i chunk
    }
    fvec4* vnv = (fvec4*)vn;
    #pragma unroll
    for (int i = 0; i < ORDER; ++i) vnv[i * F4DIM + t] = val[i];

    // 2. d and bias reparam
    const fvec4 dm = ((const fvec4*)d_mean)[t];
    const fvec4 dl = ((const fvec4*)d_logvar)[t];
    const fvec4 de = ((const fvec4*)eps_d)[t];
    fvec4 dd;
    #pragma unroll
    for (int c = 0; c < 4; ++c) dd[c] = fmaf(expf(0.5f * dl[c]), de[c], dm[c]);
    ((fvec4*)dsc)[t] = dd;

    const fvec4 bm = ((const fvec4*)b_mean)[t];
    const fvec4 bl = ((const fvec4*)b_logvar)[t];
    const fvec4 be = ((const fvec4*)eps_b)[t];
    fvec4 bb;
    #pragma unroll
    for (int c = 0; c < 4; ++c) bb[c] = fmaf(expf(0.5f * bl[c]), be[c], bm[c]);
    ((fvec4*)bias)[t] = bb;

    // 3. Gram (normalized)
    float g[NPAIR];
    {
        int p = 0;
        #pragma unroll
        for (int i = 0; i < ORDER; ++i)
            #pragma unroll
            for (int j = i; j < ORDER; ++j) {
                g[p] = val[i][0]*val[j][0] + val[i][1]*val[j][1]
                     + val[i][2]*val[j][2] + val[i][3]*val[j][3];
                ++p;
            }
    }
    #pragma unroll
    for (int off = 32; off; off >>= 1)
        #pragma unroll
        for (int p = 0; p < NPAIR; ++p) g[p] += __shfl_xor(g[p], off);
    if (lane == 0)
        #pragma unroll
        for (int p = 0; p < NPAIR; ++p) gred[wave][p] = g[p];
    __syncthreads();

    // 4. T on thread 0
    if (t == 0) {
        float G[ORDER][ORDER];
        int p = 0;
        for (int i = 0; i < ORDER; ++i)
            for (int j = i; j < ORDER; ++j) {
                float s = 0.f;
                for (int w = 0; w < NW; ++w) s += gred[w][p];
                G[i][j] = s;
                ++p;
            }
        float T[ORDER][ORDER];
        for (int i = 0; i < ORDER; ++i)
            for (int j = 0; j < ORDER; ++j) T[i][j] = 0.f;
        T[0][0] = 2.f;
        for (int j = 1; j < ORDER; ++j) {
            for (int i = 0; i < j; ++i) {
                float s = 0.f;
                for (int m = i; m < j; ++m) s += T[i][m] * G[m][j];
                T[i][j] = -2.f * s;
            }
            T[j][j] = 2.f;
        }
        for (int i = 0; i < ORDER; ++i)
            for (int j = 0; j < ORDER; ++j) Tsh[i * ORDER + j] = T[i][j];
    }
    __syncthreads();

    // 5. Md[i] = -(sum_{m>=i} T[i][m] vn_m) * d
    fvec4* Mdv = (fvec4*)Md;
    #pragma unroll
    for (int i = 0; i < ORDER; ++i) {
        fvec4 s = {0.f, 0.f, 0.f, 0.f};
        #pragma unroll
        for (int m = 0; m < ORDER; ++m) {
            if (m >= i) {
                const float tv = Tsh[i * ORDER + m];
                #pragma unroll
                for (int c = 0; c < 4; ++c) s[c] = fmaf(tv, val[m][c], s[c]);
            }
        }
        Mdv[i * F4DIM + t] = -(s * dd);
    }
}

// ---------------------------------------------------------------------------
// Main (monolithic WY, RPB=2, ONE barrier): x held in registers.
//   pass 1: p[rr][i] = row_rr . vn_i
//   xor-butterfly + one LDS hop -> complete dots
//   pass 2: out = x*d + sum_i p_i * Md_i + bias  (held x, plain store)
// __launch_bounds__(256,2): VGPR cap is empirically 128 on this toolchain
// (R3: 128, clean). (256,4) caps at 64 -> spill (R2, R8) — do NOT use.
// Live state ~90: held x 32 + p 16 + staging/addressing. 4096 blocks.
// ---------------------------------------------------------------------------
__global__ __launch_bounds__(THREADS, 2) void obd_wy(
    const float* __restrict__ x, const float* __restrict__ vn,
    const float* __restrict__ Md, const float* __restrict__ dsc,
    const float* __restrict__ bias, float* __restrict__ out)
{
    const int t = threadIdx.x;
    const int wave = t >> 6, lane = t & 63;
    const size_t row0 = (size_t)blockIdx.x * RPB;
    const fvec4* xv = (const fvec4*)x;
    const fvec4* Vv = (const fvec4*)vn;
    fvec4* ov = (fvec4*)out;

    __shared__ float red[THREADS / 64][RPB * ORDER];

    // hold x (2 rows x 4 chunks = 32 VGPR)
    fvec4 r[RPB][F4T];
    #pragma unroll
    for (int rr = 0; rr < RPB; ++rr) {
        const size_t base = (row0 + rr) * F4DIM;
        #pragma unroll
        for (int k = 0; k < F4T; ++k)
            r[rr][k] = xv[base + t + k * THREADS];
    }

    // pass 1: dots
    float p[RPB][ORDER];
    #pragma unroll
    for (int rr = 0; rr < RPB; ++rr)
        #pragma unroll
        for (int i = 0; i < ORDER; ++i) p[rr][i] = 0.f;

    #pragma unroll
    for (int k = 0; k < F4T; ++k) {
        const int idx = t + k * THREADS;
        #pragma unroll
        for (int i = 0; i < ORDER; ++i) {
            const fvec4 vc = Vv[i * F4DIM + idx];
            #pragma unroll
            for (int rr = 0; rr < RPB; ++rr)
                #pragma unroll
                for (int c = 0; c < 4; ++c)
                    p[rr][i] = fmaf(r[rr][k][c], vc[c], p[rr][i]);
        }
    }
    #pragma unroll
    for (int off = 32; off; off >>= 1)
        #pragma unroll
        for (int rr = 0; rr < RPB; ++rr)
            #pragma unroll
            for (int i = 0; i < ORDER; ++i)
                p[rr][i] += __shfl_xor(p[rr][i], off);
    if (lane == 0) {
        #pragma unroll
        for (int rr = 0; rr < RPB; ++rr)
            #pragma unroll
            for (int i = 0; i < ORDER; ++i)
                red[wave][rr * ORDER + i] = p[rr][i];
    }
    __syncthreads();
    #pragma unroll
    for (int rr = 0; rr < RPB; ++rr)
        #pragma unroll
        for (int i = 0; i < ORDER; ++i)
            p[rr][i] = red[0][rr * ORDER + i] + red[1][rr * ORDER + i]
                     + red[2][rr * ORDER + i] + red[3][rr * ORDER + i];

    // pass 2: combine on held x + plain store
    const fvec4* Mdv = (const fvec4*)Md;
    const fvec4* dv  = (const fvec4*)dsc;
    const fvec4* bv  = (const fvec4*)bias;
    #pragma unroll
    for (int k = 0; k < F4T; ++k) {
        const int idx = t + k * THREADS;
        const fvec4 dd = dv[idx];
        const fvec4 bb = bv[idx];
        fvec4 acc[RPB];
        #pragma unroll
        for (int rr = 0; rr < RPB; ++rr)
            #pragma unroll
            for (int c = 0; c < 4; ++c)
                acc[rr][c] = fmaf(r[rr][k][c], dd[c], bb[c]);
        #pragma unroll
        for (int i = 0; i < ORDER; ++i) {
            const fvec4 md = Mdv[i * F4DIM + idx];
            #pragma unroll
            for (int rr = 0; rr < RPB; ++rr)
                #pragma unroll
                for (int c = 0; c < 4; ++c)
                    acc[rr][c] = fmaf(p[rr][i], md[c], acc[rr][c]);
        }
        #pragma unroll
        for (int rr = 0; rr < RPB; ++rr)
            ov[(row0 + rr) * F4DIM + idx] = acc[rr];
    }
}

extern "C" void kernel_launch(void* const* d_in, const int* in_sizes, int n_in,
                              void* d_out, int out_size, void* d_ws, size_t ws_size,
                              hipStream_t stream) {
    const float* x        = (const float*)d_in[0];
    const float* v_mean   = (const float*)d_in[1];
    const float* v_logvar = (const float*)d_in[2];
    const float* d_mean   = (const float*)d_in[3];
    const float* d_logvar = (const float*)d_in[4];
    const float* b_mean   = (const float*)d_in[5];
    const float* b_logvar = (const float*)d_in[6];
    const float* eps_v    = (const float*)d_in[7];
    const float* eps_d    = (const float*)d_in[8];
    const float* eps_b    = (const float*)d_in[9];

    float* ws   = (float*)d_ws;
    float* vn   = ws;                        // 8*4096
    float* dsc  = vn + ORDER * FDIM;         // 4096
    float* bias = dsc + FDIM;                // 4096
    float* Md   = bias + FDIM;               // 8*4096

    obd_setup<<<1, STHREADS, 0, stream>>>(
        v_mean, v_logvar, eps_v, d_mean, d_logvar, eps_d,
        b_mean, b_logvar, eps_b, vn, dsc, bias, Md);
    obd_wy<<<NROWS / RPB, THREADS, 0, stream>>>(
        x, vn, Md, dsc, bias, (float*)d_out);
}